// Round 1
// baseline (1136.610 us; speedup 1.0000x reference)
//
#include <hip/hip_runtime.h>
#include <hip/hip_bf16.h>

// Problem constants
#define B_ 4
#define S_ 2048
#define H_ 1024
#define NH_ 16
#define HD_ 64

typedef __bf16 bf16_t;
typedef bf16_t bf16x8 __attribute__((ext_vector_type(8)));
typedef bf16_t bf16x4 __attribute__((ext_vector_type(4)));
typedef float f32x4 __attribute__((ext_vector_type(4)));

__device__ __forceinline__ f32x4 mfma16(bf16x8 a, bf16x8 b, f32x4 c) {
  return __builtin_amdgcn_mfma_f32_16x16x32_bf16(a, b, c, 0, 0, 0);
}

// ---------------------------------------------------------------------------
// Cast fp32 -> bf16 for X (8M elems) and the 4 weight matrices (1M each).
// One launch; 4 floats/thread, float4 in, bf16x4 out.
// ---------------------------------------------------------------------------
__global__ __launch_bounds__(256) void cvt_all(
    const float* __restrict__ X, const float* __restrict__ Wq,
    const float* __restrict__ Wk, const float* __restrict__ Wv,
    const float* __restrict__ Wo,
    bf16_t* __restrict__ Xb, bf16_t* __restrict__ Wqb,
    bf16_t* __restrict__ Wkb, bf16_t* __restrict__ Wvb,
    bf16_t* __restrict__ Wob) {
  size_t i = ((size_t)blockIdx.x * 256 + threadIdx.x) * 4;
  const float* src;
  bf16_t* dst;
  size_t off;
  if (i < 8388608) {  // X region
    src = X; dst = Xb; off = i;
  } else {
    size_t j = i - 8388608;
    int w = (int)(j >> 20);
    off = j & 1048575;
    switch (w) {
      case 0: src = Wq; dst = Wqb; break;
      case 1: src = Wk; dst = Wkb; break;
      case 2: src = Wv; dst = Wvb; break;
      default: src = Wo; dst = Wob; break;
    }
  }
  float4 v = *(const float4*)(src + off);
  bf16x4 o = {(bf16_t)v.x, (bf16_t)v.y, (bf16_t)v.z, (bf16_t)v.w};
  *(bf16x4*)(dst + off) = o;
}

// ---------------------------------------------------------------------------
// Generic C = A @ B^T GEMM, K=1024, bf16 in, fp32 accumulate.
// A: [M,1024] row-major bf16, Bw: [N,1024] row-major bf16.
// Block = 256 threads (4 waves); tile 64(M) x 64(N); wave does 16x64.
// Both operands are read contiguous-along-K as 16B bf16x8 frags (no LDS).
// mode 0: store bf16 head-major [B,NH,S,HD]  (M=tokens, N=h*64+d)
// mode 1: store bf16 transposed [B,NH,HD,S]  (M=h*64+d,  N=tokens)
// mode 2: store fp32 [M,1024]
// ---------------------------------------------------------------------------
__global__ __launch_bounds__(256) void gemm_bt(
    const bf16_t* __restrict__ A, const bf16_t* __restrict__ Bw,
    void* __restrict__ out, int mode) {
  int w = threadIdx.x >> 6;
  int lane = threadIdx.x & 63;
  int quad = lane >> 4, l15 = lane & 15;
  int m0 = blockIdx.x * 64 + w * 16;
  int n0 = blockIdx.y * 64;
  const bf16x8* Ap = (const bf16x8*)(A + (size_t)(m0 + l15) * 1024) + quad;
  const bf16x8* Bp = (const bf16x8*)(Bw + (size_t)(n0 + l15) * 1024) + quad;
  f32x4 acc[4] = {};
#pragma unroll 2
  for (int ks = 0; ks < 32; ++ks) {
    bf16x8 a  = Ap[ks * 4];
    bf16x8 b0 = Bp[ks * 4];
    bf16x8 b1 = Bp[2048 + ks * 4];
    bf16x8 b2 = Bp[4096 + ks * 4];
    bf16x8 b3 = Bp[6144 + ks * 4];
    acc[0] = mfma16(a, b0, acc[0]);
    acc[1] = mfma16(a, b1, acc[1]);
    acc[2] = mfma16(a, b2, acc[2]);
    acc[3] = mfma16(a, b3, acc[3]);
  }
  // C/D layout: col = lane&15 (n within 16-tile), row = quad*4 + reg (m)
  if (mode == 2) {
    float* O = (float*)out;
#pragma unroll
    for (int t = 0; t < 4; ++t)
#pragma unroll
      for (int r = 0; r < 4; ++r)
        O[(size_t)(m0 + quad * 4 + r) * 1024 + n0 + t * 16 + l15] = acc[t][r];
  } else if (mode == 0) {
    bf16_t* O = (bf16_t*)out;
    int h = blockIdx.y;  // N-tile == one head exactly (64 == HD)
#pragma unroll
    for (int t = 0; t < 4; ++t)
#pragma unroll
      for (int r = 0; r < 4; ++r) {
        int tok = m0 + quad * 4 + r;
        int b = tok >> 11, s = tok & 2047;
        O[(((size_t)b * NH_ + h) * S_ + s) * HD_ + t * 16 + l15] =
            (bf16_t)acc[t][r];
      }
  } else {
    bf16_t* O = (bf16_t*)out;
#pragma unroll
    for (int t = 0; t < 4; ++t)
#pragma unroll
      for (int r = 0; r < 4; ++r) {
        int dg = m0 + quad * 4 + r;      // global head-dim index
        int hh = dg >> 6, d = dg & 63;
        int tok = n0 + t * 16 + l15;     // lanes -> consecutive s: coalesced
        int b = tok >> 11, s = tok & 2047;
        O[((size_t)(b * NH_ + hh) * HD_ + d) * S_ + s] = (bf16_t)acc[t][r];
      }
  }
}

// ---------------------------------------------------------------------------
// Flash attention: grid (S/64, B*NH), block 256 = 4 independent waves.
// Each wave: 16 q-rows, online softmax (log2 domain), K chunks of 64.
// Q,K: [B,NH,S,HD] bf16. Vt: [B,NH,HD,S] bf16 (pre-transposed so PV B-frags
// are contiguous 16B loads). P goes C-layout -> LDS -> A-layout (stride 72:
// 144B rows keep ds_read_b128 16B-aligned and spread banks).
// ---------------------------------------------------------------------------
__global__ __launch_bounds__(256) void attn_fused(
    const bf16_t* __restrict__ Q, const bf16_t* __restrict__ K,
    const bf16_t* __restrict__ Vt, const float* __restrict__ mask,
    bf16_t* __restrict__ Oa) {
  __shared__ __align__(16) bf16_t plds[4][16 * 72];
  int w = threadIdx.x >> 6;
  int lane = threadIdx.x & 63;
  int quad = lane >> 4, l15 = lane & 15;
  int bh = blockIdx.y;
  int b = bh >> 4, h = bh & 15;
  int q0 = blockIdx.x * 64 + w * 16;
  const bf16_t* Qh = Q + (size_t)bh * (S_ * HD_);
  const bf16_t* Kh = K + (size_t)bh * (S_ * HD_);
  const bf16_t* Vh = Vt + (size_t)bh * (HD_ * S_);
  const float* mb = mask + b * S_;
  bf16_t* pl = plds[w];

  // Q A-frags: A[m=lane&15][k=quad*8+j], k-steps 0..31 / 32..63
  bf16x8 aq0 = *(const bf16x8*)(Qh + (size_t)(q0 + l15) * HD_ + quad * 8);
  bf16x8 aq1 = *(const bf16x8*)(Qh + (size_t)(q0 + l15) * HD_ + 32 + quad * 8);

  f32x4 oc[4] = {};
  float mrow[4], lrow[4];
#pragma unroll
  for (int r = 0; r < 4; ++r) { mrow[r] = -3.0e38f; lrow[r] = 0.f; }
  const float scl = 0.125f * 1.4426950408889634f;  // HD^-0.5 * log2(e)

  for (int c = 0; c < 32; ++c) {
    int kv0 = c * 64;
    // ---- scores = Q @ K^T (16 x 64) ----
    f32x4 sc[4] = {};
    const bf16_t* Kc = Kh + (size_t)(kv0 + l15) * HD_ + quad * 8;
#pragma unroll
    for (int t = 0; t < 4; ++t) {
      bf16x8 b0 = *(const bf16x8*)(Kc + t * (16 * HD_));
      bf16x8 b1 = *(const bf16x8*)(Kc + t * (16 * HD_) + 32);
      sc[t] = mfma16(aq0, b0, sc[t]);
      sc[t] = mfma16(aq1, b1, sc[t]);
    }
    // scale + additive mask, in log2 domain
#pragma unroll
    for (int t = 0; t < 4; ++t) {
      float mk = mb[kv0 + t * 16 + l15] * 1.4426950408889634f;
#pragma unroll
      for (int r = 0; r < 4; ++r) sc[t][r] = sc[t][r] * scl + mk;
    }
    // ---- row max: reduce over 4 col-tiles, then 16 lanes of the group ----
    float rmax[4];
#pragma unroll
    for (int r = 0; r < 4; ++r) {
      float v = fmaxf(fmaxf(sc[0][r], sc[1][r]), fmaxf(sc[2][r], sc[3][r]));
      v = fmaxf(v, __shfl_xor(v, 1));
      v = fmaxf(v, __shfl_xor(v, 2));
      v = fmaxf(v, __shfl_xor(v, 4));
      v = fmaxf(v, __shfl_xor(v, 8));
      rmax[r] = v;
    }
    float alpha[4];
#pragma unroll
    for (int r = 0; r < 4; ++r) {
      float mn = fmaxf(mrow[r], rmax[r]);
      alpha[r] = exp2f(mrow[r] - mn);
      mrow[r] = mn;
    }
    // ---- P = exp2(s - m); row sums; write P to wave-private LDS ----
    float rsum[4] = {0.f, 0.f, 0.f, 0.f};
#pragma unroll
    for (int t = 0; t < 4; ++t)
#pragma unroll
      for (int r = 0; r < 4; ++r) {
        float p = exp2f(sc[t][r] - mrow[r]);
        rsum[r] += p;
        pl[(quad * 4 + r) * 72 + t * 16 + l15] = (bf16_t)p;
      }
#pragma unroll
    for (int r = 0; r < 4; ++r) {
      float v = rsum[r];
      v += __shfl_xor(v, 1);
      v += __shfl_xor(v, 2);
      v += __shfl_xor(v, 4);
      v += __shfl_xor(v, 8);
      lrow[r] = lrow[r] * alpha[r] + v;
    }
    // rescale O accumulator rows (row = quad*4 + r matches alpha indexing)
#pragma unroll
    for (int t = 0; t < 4; ++t)
#pragma unroll
      for (int r = 0; r < 4; ++r) oc[t][r] *= alpha[r];
    // ---- O += P @ V ----  (P A-frags from LDS, V B-frags from Vt)
    bf16x8 ap0 = *(const bf16x8*)(pl + l15 * 72 + quad * 8);
    bf16x8 ap1 = *(const bf16x8*)(pl + l15 * 72 + 32 + quad * 8);
    const bf16_t* Vc = Vh + (size_t)l15 * S_ + kv0 + quad * 8;
#pragma unroll
    for (int t = 0; t < 4; ++t) {
      bf16x8 v0 = *(const bf16x8*)(Vc + (size_t)t * 16 * S_);
      bf16x8 v1 = *(const bf16x8*)(Vc + (size_t)t * 16 * S_ + 32);
      oc[t] = mfma16(ap0, v0, oc[t]);
      oc[t] = mfma16(ap1, v1, oc[t]);
    }
  }
  // ---- epilogue: O /= l, store bf16 [B,S,H] ----
  float inv[4];
#pragma unroll
  for (int r = 0; r < 4; ++r) inv[r] = 1.0f / lrow[r];
#pragma unroll
  for (int t = 0; t < 4; ++t)
#pragma unroll
    for (int r = 0; r < 4; ++r) {
      size_t tok = (size_t)b * S_ + q0 + quad * 4 + r;
      Oa[tok * H_ + h * HD_ + t * 16 + l15] = (bf16_t)(oc[t][r] * inv[r]);
    }
}

// ---------------------------------------------------------------------------
extern "C" void kernel_launch(void* const* d_in, const int* in_sizes, int n_in,
                              void* d_out, int out_size, void* d_ws,
                              size_t ws_size, hipStream_t stream) {
  const float* hs   = (const float*)d_in[0];
  const float* mask = (const float*)d_in[1];
  const float* Wq   = (const float*)d_in[2];
  const float* Wk   = (const float*)d_in[3];
  const float* Wv   = (const float*)d_in[4];
  const float* Wo   = (const float*)d_in[5];
  float* out = (float*)d_out;

  // workspace carve-up (72 MB total)
  char* p = (char*)d_ws;
  bf16_t* Xb  = (bf16_t*)p; p += (size_t)8192 * 1024 * 2;  // 16 MB
  bf16_t* Wqb = (bf16_t*)p; p += (size_t)1024 * 1024 * 2;
  bf16_t* Wkb = (bf16_t*)p; p += (size_t)1024 * 1024 * 2;
  bf16_t* Wvb = (bf16_t*)p; p += (size_t)1024 * 1024 * 2;
  bf16_t* Wob = (bf16_t*)p; p += (size_t)1024 * 1024 * 2;
  bf16_t* q_ws  = (bf16_t*)p; p += (size_t)8192 * 1024 * 2;  // [B,NH,S,HD]
  bf16_t* k_ws  = (bf16_t*)p; p += (size_t)8192 * 1024 * 2;  // [B,NH,S,HD]
  bf16_t* vt_ws = (bf16_t*)p; p += (size_t)8192 * 1024 * 2;  // [B,NH,HD,S]
  bf16_t* attn_b = Xb;  // Xb dead after Vt GEMM; reuse for attention output

  cvt_all<<<12288, 256, 0, stream>>>(hs, Wq, Wk, Wv, Wo, Xb, Wqb, Wkb, Wvb,
                                     Wob);
  gemm_bt<<<dim3(128, 16), 256, 0, stream>>>(Xb, Wqb, q_ws, 0);   // Q
  gemm_bt<<<dim3(128, 16), 256, 0, stream>>>(Xb, Wkb, k_ws, 0);   // K
  gemm_bt<<<dim3(16, 128), 256, 0, stream>>>(Wvb, Xb, vt_ws, 1);  // V^T
  attn_fused<<<dim3(32, 64), 256, 0, stream>>>(q_ws, k_ws, vt_ws, mask,
                                               attn_b);
  gemm_bt<<<dim3(128, 16), 256, 0, stream>>>(attn_b, Wob, out, 2);  // out proj
}

// Round 4
// 368.716 us; speedup vs baseline: 3.0826x; 3.0826x over previous
//
#include <hip/hip_runtime.h>
#include <hip/hip_bf16.h>

// Problem constants
#define B_ 4
#define S_ 2048
#define H_ 1024
#define NH_ 16
#define HD_ 64

typedef __bf16 bf16_t;
typedef bf16_t bf16x8 __attribute__((ext_vector_type(8)));
typedef bf16_t bf16x4 __attribute__((ext_vector_type(4)));
typedef float f32x4 __attribute__((ext_vector_type(4)));

__device__ __forceinline__ f32x4 mfma16(bf16x8 a, bf16x8 b, f32x4 c) {
  return __builtin_amdgcn_mfma_f32_16x16x32_bf16(a, b, c, 0, 0, 0);
}

// async 16B global->LDS. lds ptr must be wave-uniform; HW adds lane*16.
__device__ __forceinline__ void gll16(const bf16_t* g, bf16_t* l) {
  __builtin_amdgcn_global_load_lds(
      (const __attribute__((address_space(1))) void*)g,
      (__attribute__((address_space(3))) void*)l, 16, 0, 0);
}

// Read a 16B A/B fragment from a [rows][64] bf16 LDS tile whose 16B chunks
// are XOR-swizzled: LDS[row][slot] holds global chunk slot^(row&7).
__device__ __forceinline__ bf16x8 frag64(const bf16_t* lds, int row,
                                         int kchunk) {
  return *(const bf16x8*)((const char*)lds + row * 128 +
                          ((kchunk ^ (row & 7)) << 4));
}

// Stage a 128x64 bf16 tile (rows from gbase, row stride gstride elems) into
// a 16KB LDS tile with the XOR chunk swizzle. 4 waves x 4 segs x 1KB.
// (m97-proven global_load_lds pattern; single-buffered 2-barrier loop.)
__device__ __forceinline__ void stage128(const bf16_t* gbase, int gstride,
                                         bf16_t* lds, int w, int lane) {
#pragma unroll
  for (int j = 0; j < 4; ++j) {
    int seg = w * 4 + j;
    int row = seg * 8 + (lane >> 3);
    int chunk = (lane & 7) ^ (row & 7);
    gll16(gbase + (size_t)row * gstride + chunk * 8, lds + seg * 512);
  }
}

// ---------------------------------------------------------------------------
// Cast fp32 -> bf16 for X (8M elems) and the 4 weight matrices (1M each).
// ---------------------------------------------------------------------------
__global__ __launch_bounds__(256) void cvt_all(
    const float* __restrict__ X, const float* __restrict__ Wq,
    const float* __restrict__ Wk, const float* __restrict__ Wv,
    const float* __restrict__ Wo,
    bf16_t* __restrict__ Xb, bf16_t* __restrict__ Wqb,
    bf16_t* __restrict__ Wkb, bf16_t* __restrict__ Wvb,
    bf16_t* __restrict__ Wob) {
  size_t i = ((size_t)blockIdx.x * 256 + threadIdx.x) * 4;
  const float* src;
  bf16_t* dst;
  size_t off;
  if (i < 8388608) {
    src = X; dst = Xb; off = i;
  } else {
    size_t j = i - 8388608;
    int w = (int)(j >> 20);
    off = j & 1048575;
    switch (w) {
      case 0: src = Wq; dst = Wqb; break;
      case 1: src = Wk; dst = Wkb; break;
      case 2: src = Wv; dst = Wvb; break;
      default: src = Wo; dst = Wob; break;
    }
  }
  float4 v = *(const float4*)(src + off);
  bf16x4 o = {(bf16_t)v.x, (bf16_t)v.y, (bf16_t)v.z, (bf16_t)v.w};
  *(bf16x4*)(dst + off) = o;
}

// ---------------------------------------------------------------------------
// C = A @ B^T, K=1024, bf16 in, fp32 acc. m97 structure: 128x128 tile, BK=64,
// global_load_lds staging, XOR-swizzled LDS, 4 waves (2x2), 32 MFMA / BK.
// mode 0: store bf16 head-major [B,NH,S,HD]
// mode 1: store bf16 transposed [B,NH,HD,S]
// mode 2: store fp32 [M,1024]
// ---------------------------------------------------------------------------
__global__ __launch_bounds__(256) void gemm_bt(
    const bf16_t* __restrict__ A, const bf16_t* __restrict__ Bw,
    void* __restrict__ out, int mode) {
  __shared__ __align__(16) bf16_t As[8192];
  __shared__ __align__(16) bf16_t Bs[8192];
  int w = threadIdx.x >> 6, lane = threadIdx.x & 63;
  int quad = lane >> 4, l15 = lane & 15;
  int wm = w >> 1, wn = w & 1;
  int Mb = blockIdx.x * 128, Nb = blockIdx.y * 128;
  f32x4 acc[4][4] = {};
  for (int kb = 0; kb < 16; ++kb) {
    stage128(A + (size_t)Mb * 1024 + kb * 64, 1024, As, w, lane);
    stage128(Bw + (size_t)Nb * 1024 + kb * 64, 1024, Bs, w, lane);
    __syncthreads();
#pragma unroll
    for (int kt = 0; kt < 2; ++kt) {
      bf16x8 af[4], bfr[4];
#pragma unroll
      for (int i = 0; i < 4; ++i) {
        af[i] = frag64(As, wm * 64 + i * 16 + l15, kt * 4 + quad);
        bfr[i] = frag64(Bs, wn * 64 + i * 16 + l15, kt * 4 + quad);
      }
#pragma unroll
      for (int mt = 0; mt < 4; ++mt)
#pragma unroll
        for (int nt = 0; nt < 4; ++nt)
          acc[mt][nt] = mfma16(af[mt], bfr[nt], acc[mt][nt]);
    }
    __syncthreads();
  }
  // C/D layout: col = l15 (n), row = quad*4 + r (m)
#pragma unroll
  for (int mt = 0; mt < 4; ++mt) {
    int m0t = Mb + wm * 64 + mt * 16;
#pragma unroll
    for (int nt = 0; nt < 4; ++nt) {
      int n0t = Nb + wn * 64 + nt * 16;
      if (mode == 2) {
        float* O = (float*)out;
#pragma unroll
        for (int r = 0; r < 4; ++r)
          O[(size_t)(m0t + quad * 4 + r) * 1024 + n0t + l15] = acc[mt][nt][r];
      } else if (mode == 0) {
        bf16_t* O = (bf16_t*)out;
        int h = n0t >> 6, d = (n0t & 63) + l15;
#pragma unroll
        for (int r = 0; r < 4; ++r) {
          int tok = m0t + quad * 4 + r;
          int b = tok >> 11, s = tok & 2047;
          O[(((size_t)b * NH_ + h) * S_ + s) * HD_ + d] = (bf16_t)acc[mt][nt][r];
        }
      } else {
        bf16_t* O = (bf16_t*)out;
#pragma unroll
        for (int r = 0; r < 4; ++r) {
          int dg = m0t + quad * 4 + r;
          int hh = dg >> 6, d = dg & 63;
          int tok = n0t + l15;
          int b = tok >> 11, s = tok & 2047;
          O[((size_t)(b * NH_ + hh) * HD_ + d) * S_ + s] = (bf16_t)acc[mt][nt][r];
        }
      }
    }
  }
}

// ---------------------------------------------------------------------------
// Flash attention, transposed orientation. grid (S/128, B*NH), block 256.
// Each wave: 32 q-cols. Per 64-key chunk:
//   S^T = K @ Q^T  (C-layout: row=key, col=q)  -> softmax over rows (2 shfl)
//   P packed 4-keys-at-a-time into LDS [q][key] (8B writes)
//   O^T += Vt @ P^T  (A=Vt rows from LDS, B=P rows from LDS)
// K/V staged once per block via REGISTER pipeline: chunk c+1 loaded into
// per-thread registers (global_load_dwordx4, in flight during compute of c),
// written to single-buffered swizzled LDS at the top of iteration c+1.
// No global_load_lds in this kernel (de-risk).
// ---------------------------------------------------------------------------
__global__ __launch_bounds__(256) void attn_fused(
    const bf16_t* __restrict__ Q, const bf16_t* __restrict__ K,
    const bf16_t* __restrict__ Vt, const float* __restrict__ mask,
    bf16_t* __restrict__ Oa) {
  __shared__ __align__(16) bf16_t Ks[4096];
  __shared__ __align__(16) bf16_t Vs[4096];
  __shared__ __align__(16) bf16_t Ps[4][32 * 72];
  int w = threadIdx.x >> 6, lane = threadIdx.x & 63;
  int quad = lane >> 4, l15 = lane & 15;
  int bh = blockIdx.y;
  int b = bh >> 4, h = bh & 15;
  int q0 = blockIdx.x * 128 + w * 32;
  const bf16_t* Qh = Q + (size_t)bh * (S_ * HD_);
  const bf16_t* Kh = K + (size_t)bh * (S_ * HD_);
  const bf16_t* Vh = Vt + (size_t)bh * (HD_ * S_);
  const float* mb = mask + b * S_;
  bf16_t* pw = Ps[w];
  const float LOG2E = 1.4426950408889634f;
  const float scl = 0.125f * LOG2E;  // HD^-0.5 * log2(e)

  // staging geometry: thread handles segs w*2+j (j=0,1) of each 8KB tile;
  // within a seg: row = seg*8 + (lane>>3), slot = lane&7, global chunk =
  // slot ^ (row&7); LDS elem offset = seg*512 + lane*8 (16B per thread).
  int srow[2], schunk[2], soff[2];
#pragma unroll
  for (int j = 0; j < 2; ++j) {
    int seg = w * 2 + j;
    srow[j] = seg * 8 + (lane >> 3);
    schunk[j] = (lane & 7) ^ (srow[j] & 7);
    soff[j] = seg * 512 + lane * 8;
  }

  // Q B-frags: [n=q=l15][k=d=quad*8+j], nt in {0,1}, kt in {0,1}
  bf16x8 qf[2][2];
#pragma unroll
  for (int nt = 0; nt < 2; ++nt)
#pragma unroll
    for (int kt = 0; kt < 2; ++kt)
      qf[nt][kt] = *(const bf16x8*)(Qh + (size_t)(q0 + nt * 16 + l15) * HD_ +
                                    kt * 32 + quad * 8);

  f32x4 oc[4][2] = {};
  float mrow[2] = {-3.0e38f, -3.0e38f}, lrow[2] = {0.f, 0.f};

  // prologue: load chunk 0 into registers
  bf16x8 kreg[2], vreg[2];
#pragma unroll
  for (int j = 0; j < 2; ++j) {
    kreg[j] = *(const bf16x8*)(Kh + (size_t)srow[j] * HD_ + schunk[j] * 8);
    vreg[j] = *(const bf16x8*)(Vh + (size_t)srow[j] * S_ + schunk[j] * 8);
  }

  for (int c = 0; c < 32; ++c) {
    __syncthreads();  // all waves done reading LDS chunk c-1
#pragma unroll
    for (int j = 0; j < 2; ++j) {
      *(bf16x8*)(Ks + soff[j]) = kreg[j];
      *(bf16x8*)(Vs + soff[j]) = vreg[j];
    }
    __syncthreads();  // LDS chunk c visible to all waves
    if (c + 1 < 32) {
      const bf16_t* Kc = Kh + (size_t)(c + 1) * 64 * HD_;
      const bf16_t* Vc = Vh + (size_t)(c + 1) * 64;
#pragma unroll
      for (int j = 0; j < 2; ++j) {
        kreg[j] = *(const bf16x8*)(Kc + (size_t)srow[j] * HD_ + schunk[j] * 8);
        vreg[j] = *(const bf16x8*)(Vc + (size_t)srow[j] * S_ + schunk[j] * 8);
      }
    }
    // ---- S^T = K @ Q^T : sc[mt][nt], row=key=mt*16+quad*4+r, col=q ----
    f32x4 sc[4][2] = {};
#pragma unroll
    for (int kt = 0; kt < 2; ++kt) {
      bf16x8 kf[4];
#pragma unroll
      for (int mt = 0; mt < 4; ++mt)
        kf[mt] = frag64(Ks, mt * 16 + l15, kt * 4 + quad);
#pragma unroll
      for (int mt = 0; mt < 4; ++mt)
#pragma unroll
        for (int nt = 0; nt < 2; ++nt)
          sc[mt][nt] = mfma16(kf[mt], qf[nt][kt], sc[mt][nt]);
    }
    // ---- scale + mask (log2 domain). mask indexed by key. ----
#pragma unroll
    for (int mt = 0; mt < 4; ++mt) {
      f32x4 mk = *(const f32x4*)(mb + c * 64 + mt * 16 + quad * 4);
#pragma unroll
      for (int nt = 0; nt < 2; ++nt)
#pragma unroll
        for (int r = 0; r < 4; ++r)
          sc[mt][nt][r] = sc[mt][nt][r] * scl + mk[r] * LOG2E;
    }
    // ---- per-q online softmax; write P to wave-private LDS ----
#pragma unroll
    for (int nt = 0; nt < 2; ++nt) {
      float v = sc[0][nt][0];
#pragma unroll
      for (int mt = 0; mt < 4; ++mt)
#pragma unroll
        for (int r = 0; r < 4; ++r) v = fmaxf(v, sc[mt][nt][r]);
      v = fmaxf(v, __shfl_xor(v, 16));
      v = fmaxf(v, __shfl_xor(v, 32));
      float mn = fmaxf(mrow[nt], v);
      float al = __builtin_exp2f(mrow[nt] - mn);
      mrow[nt] = mn;
      float rs = 0.f;
#pragma unroll
      for (int mt = 0; mt < 4; ++mt) {
        bf16x4 p4;
#pragma unroll
        for (int r = 0; r < 4; ++r) {
          float p = __builtin_exp2f(sc[mt][nt][r] - mn);
          rs += p;
          p4[r] = (bf16_t)p;
        }
        *(bf16x4*)(pw + (nt * 16 + l15) * 72 + mt * 16 + quad * 4) = p4;
      }
      rs += __shfl_xor(rs, 16);
      rs += __shfl_xor(rs, 32);
      lrow[nt] = lrow[nt] * al + rs;
#pragma unroll
      for (int dt = 0; dt < 4; ++dt)
#pragma unroll
        for (int r = 0; r < 4; ++r) oc[dt][nt][r] *= al;
    }
    // ---- O^T += Vt @ P^T : A=V[d][key] (LDS), B=P[q][key] (LDS) ----
#pragma unroll
    for (int kt = 0; kt < 2; ++kt) {
      bf16x8 pf[2];
#pragma unroll
      for (int nt = 0; nt < 2; ++nt)
        pf[nt] = *(const bf16x8*)(pw + (nt * 16 + l15) * 72 + kt * 32 +
                                  quad * 8);
#pragma unroll
      for (int dt = 0; dt < 4; ++dt) {
        bf16x8 vf = frag64(Vs, dt * 16 + l15, kt * 4 + quad);
#pragma unroll
        for (int nt = 0; nt < 2; ++nt)
          oc[dt][nt] = mfma16(vf, pf[nt], oc[dt][nt]);
      }
    }
  }
  // ---- epilogue: O^T/l -> Oa[b, s=q, h*64+d], packed 8B stores ----
  float inv[2] = {1.0f / lrow[0], 1.0f / lrow[1]};
#pragma unroll
  for (int dt = 0; dt < 4; ++dt)
#pragma unroll
    for (int nt = 0; nt < 2; ++nt) {
      bf16x4 o4;
#pragma unroll
      for (int r = 0; r < 4; ++r) o4[r] = (bf16_t)(oc[dt][nt][r] * inv[nt]);
      size_t tok = (size_t)b * S_ + q0 + nt * 16 + l15;
      *(bf16x4*)(Oa + tok * H_ + h * HD_ + dt * 16 + quad * 4) = o4;
    }
}

// ---------------------------------------------------------------------------
extern "C" void kernel_launch(void* const* d_in, const int* in_sizes, int n_in,
                              void* d_out, int out_size, void* d_ws,
                              size_t ws_size, hipStream_t stream) {
  const float* hs   = (const float*)d_in[0];
  const float* mask = (const float*)d_in[1];
  const float* Wq   = (const float*)d_in[2];
  const float* Wk   = (const float*)d_in[3];
  const float* Wv   = (const float*)d_in[4];
  const float* Wo   = (const float*)d_in[5];
  float* out = (float*)d_out;

  char* p = (char*)d_ws;
  bf16_t* Xb  = (bf16_t*)p; p += (size_t)8192 * 1024 * 2;
  bf16_t* Wqb = (bf16_t*)p; p += (size_t)1024 * 1024 * 2;
  bf16_t* Wkb = (bf16_t*)p; p += (size_t)1024 * 1024 * 2;
  bf16_t* Wvb = (bf16_t*)p; p += (size_t)1024 * 1024 * 2;
  bf16_t* Wob = (bf16_t*)p; p += (size_t)1024 * 1024 * 2;
  bf16_t* q_ws  = (bf16_t*)p; p += (size_t)8192 * 1024 * 2;  // [B,NH,S,HD]
  bf16_t* k_ws  = (bf16_t*)p; p += (size_t)8192 * 1024 * 2;  // [B,NH,S,HD]
  bf16_t* vt_ws = (bf16_t*)p; p += (size_t)8192 * 1024 * 2;  // [B,NH,HD,S]
  bf16_t* attn_b = Xb;  // Xb dead after Vt GEMM; reuse for attention output

  cvt_all<<<12288, 256, 0, stream>>>(hs, Wq, Wk, Wv, Wo, Xb, Wqb, Wkb, Wvb,
                                     Wob);
  gemm_bt<<<dim3(64, 8), 256, 0, stream>>>(Xb, Wqb, q_ws, 0);   // Q
  gemm_bt<<<dim3(64, 8), 256, 0, stream>>>(Xb, Wkb, k_ws, 0);   // K
  gemm_bt<<<dim3(8, 64), 256, 0, stream>>>(Wvb, Xb, vt_ws, 1);  // V^T
  attn_fused<<<dim3(16, 64), 256, 0, stream>>>(q_ws, k_ws, vt_ws, mask,
                                               attn_b);
  gemm_bt<<<dim3(64, 8), 256, 0, stream>>>(attn_b, Wob, out, 2);  // out proj
}